// Round 4
// baseline (330405.933 us; speedup 1.0000x reference)
//
#include <hip/hip_runtime.h>
#include <math.h>

#define B 32
#define SEQ 1024
#define H 512
#define NWG 64
#define NT 256
#define CHUNK 128
#define COLS 24             // output cols per WG (64*24 = 1536 = 3 units x 512)
#define FLAG_STRIDE 16

__device__ __forceinline__ float sigf(float v){ return 1.0f/(1.0f+expf(-v)); }

// Relaxed agent-scope atomics: coherent LLC access, no wbl2/inv cache maintenance.
__device__ __forceinline__ float ldc(const float* p){
    return __hip_atomic_load(p, __ATOMIC_RELAXED, __HIP_MEMORY_SCOPE_AGENT);
}
__device__ __forceinline__ void stc(float* p, float v){
    __hip_atomic_store(p, v, __ATOMIC_RELAXED, __HIP_MEMORY_SCOPE_AGENT);
}
__device__ __forceinline__ unsigned ldcu(const unsigned* p){
    return __hip_atomic_load(p, __ATOMIC_RELAXED, __HIP_MEMORY_SCOPE_AGENT);
}
__device__ __forceinline__ void stcu(unsigned* p, unsigned v){
    __hip_atomic_store(p, v, __ATOMIC_RELAXED, __HIP_MEMORY_SCOPE_AGENT);
}

// All-to-all barrier: each WG stores its flag; wave 0 of every WG polls all 64.
// vmcnt(0) before arrival (per-wave, all waves execute it) orders data->flag.
__device__ __forceinline__ void grid_sync(unsigned* flags, unsigned gen){
    asm volatile("s_waitcnt vmcnt(0)" ::: "memory");
    __syncthreads();
    if (threadIdx.x == 0)
        stcu(&flags[blockIdx.x * FLAG_STRIDE], gen);
    if (threadIdx.x < NWG){
        while (ldcu(&flags[threadIdx.x * FLAG_STRIDE]) < gen)
            __builtin_amdgcn_s_sleep(1);
    }
    __syncthreads();
}

// Stage one K-chunk of a [32][*] matrix into LDS xh[kk][b]. COH: LLC-coherent.
// Write banks: 2-way max (verified). srcStride in elements.
template<bool COH>
__device__ __forceinline__ void stage(float (*xh)[B+1], const float* src,
                                      int kc, size_t srcStride){
#pragma unroll
    for (int j = 0; j < (CHUNK*B)/NT; ++j){   // 16
        int idx = j*NT + (int)threadIdx.x;
        int b  = idx >> 7;                    // /CHUNK
        int kk = idx & (CHUNK-1);
        const float* p = src + (size_t)b*srcStride + (size_t)(kc + kk);
        xh[kk][b] = COH ? ldc(p) : *p;
    }
}

struct Cfg {
    const float* wq[6];   // per-quad weight base (col offset folded in), row stride H
    int qsplit;           // quads [0,qsplit) read A0, rest read A1
    const float* A0;      // coherent source, [32][H]
    const float* A1;      // cached source, row stride SEQ*H
};

// MODE 0: all quads A1; MODE 1: all quads A0; MODE 2: mixed (runtime qsplit)
template<int MODE>
__device__ __forceinline__ void matcore(const Cfg& cf, float (*xh0)[B+1],
        float (*xh1)[B+1], float (*red)[8][25], float sout[3])
{
    const int tid = threadIdx.x;
    const int b = tid >> 3, ks = tid & 7;
    float acc[6][4];
#pragma unroll
    for (int q=0;q<6;++q){ acc[q][0]=acc[q][1]=acc[q][2]=acc[q][3]=0.f; }

    for (int kc = 0; kc < H; kc += CHUNK){
        if (MODE != 0) stage<true >(xh0, cf.A0, kc, H);
        if (MODE != 1) stage<false>(xh1, cf.A1, kc, (size_t)SEQ*H);
        __syncthreads();
#pragma unroll 2
        for (int i = 0; i < CHUNK/8; ++i){     // 16
            int ii = (i + ks*2) & (CHUNK/8 - 1);   // rotate: spreads banks across ks
            int k  = ks*(CHUNK/8) + ii;
            float a0 = (MODE != 0) ? xh0[k][b] : 0.f;
            float a1 = (MODE != 1) ? xh1[k][b] : 0.f;
            size_t off = (size_t)(kc + k) * H;
#pragma unroll
            for (int q = 0; q < 6; ++q){
                float av = (MODE==1) ? a0 : (MODE==0) ? a1
                                          : ((q < cf.qsplit) ? a0 : a1);
                const float4 w = *(const float4*)(cf.wq[q] + off);
                acc[q][0] = fmaf(av, w.x, acc[q][0]);
                acc[q][1] = fmaf(av, w.y, acc[q][1]);
                acc[q][2] = fmaf(av, w.z, acc[q][2]);
                acc[q][3] = fmaf(av, w.w, acc[q][3]);
            }
        }
        __syncthreads();
    }
#pragma unroll
    for (int q=0;q<6;++q)
#pragma unroll
        for (int e=0;e<4;++e) red[b][ks][q*4+e] = acc[q][e];
    __syncthreads();
    const int cb = (tid&7)*3;
#pragma unroll
    for (int e=0;e<3;++e){
        float s = 0.f;
#pragma unroll
        for (int j=0;j<8;++j) s += red[b][j][cb+e];
        sout[e] = s;
    }
}

__device__ __forceinline__ void run_unit(const Cfg& cf, float (*xh0)[B+1],
        float (*xh1)[B+1], float (*red)[8][25], float sout[3])
{
    if (cf.qsplit == 6)      matcore<1>(cf, xh0, xh1, red, sout);
    else if (cf.qsplit == 0) matcore<0>(cf, xh0, xh1, red, sout);
    else                     matcore<2>(cf, xh0, xh1, red, sout);
}

// Phase 1 of step t: cols {0-511: z_h, 512-1023: r_h, 1024-1535: xgo(t)}
__device__ void phase1(int t, const float* xsrc,
    const float* Wz, const float* Wr, const float* Wo, const float* bo,
    float* zbuf, float* rhbuf, float* xgz, float* xgr, float* xgo, float* hbuf,
    float (*xh0)[B+1], float (*xh1)[B+1], float (*red)[8][25])
{
    const int c0 = blockIdx.x * COLS;
    Cfg cf;
    int d = 1024 - c0;
    cf.qsplit = (d <= 0) ? 0 : (d >= COLS ? 6 : (d >> 2));
#pragma unroll
    for (int q=0;q<6;++q){
        int col = c0 + 4*q;
        int n = col & (H-1);
        cf.wq[q] = (col < 512)  ? (Wz + (size_t)512*H + n)
                 : (col < 1024) ? (Wr + (size_t)512*H + n)
                 :                (Wo + n);
    }
    cf.A0 = hbuf;
    cf.A1 = xsrc + (size_t)t*H;
    float s[3];
    run_unit(cf, xh0, xh1, red, s);

    const int tid = threadIdx.x;
    const int b2 = tid>>3, cb = (tid&7)*3;
#pragma unroll
    for (int e=0;e<3;++e){
        int col = c0 + cb + e;
        int n = col & (H-1);
        int o = b2*H + n;
        if (col < 512){
            stc(&zbuf[o], sigf(s[e] + ldc(&xgz[o])));
        } else if (col < 1024){
            stc(&rhbuf[o], sigf(s[e] + ldc(&xgr[o])) * ldc(&hbuf[o]));
        } else {
            stc(&xgo[o], s[e] + bo[n]);
        }
    }
}

// Phase 2 of step t: cols {0-511: o_h + h-update, 512-1023: xgz(t+1), 1024-1535: xgr(t+1)}
// t = -1: prologue (only xg units effective).
template<int PASS>
__device__ void phase2(int t, const float* xsrc,
    const float* Wz, const float* Wr, const float* Wo,
    const float* bz, const float* br,
    float* zbuf, float* rhbuf, float* xgz, float* xgr, float* xgo,
    float* hbuf, float* out,
    float (*xh0)[B+1], float (*xh1)[B+1], float (*red)[8][25])
{
    const int c0 = blockIdx.x * COLS;
    Cfg cf;
    int d = 512 - c0;
    cf.qsplit = (d <= 0) ? 0 : (d >= COLS ? 6 : (d >> 2));
#pragma unroll
    for (int q=0;q<6;++q){
        int col = c0 + 4*q;
        int n = col & (H-1);
        cf.wq[q] = (col < 512)  ? (Wo + (size_t)512*H + n)
                 : (col < 1024) ? (Wz + n)
                 :                (Wr + n);
    }
    cf.A0 = rhbuf;
    int tn = t + 1; if (tn > SEQ-1) tn = SEQ-1;   // clamp (results discarded at tail)
    cf.A1 = xsrc + (size_t)tn*H;
    float s[3];
    run_unit(cf, xh0, xh1, red, s);

    const int tid = threadIdx.x;
    const int b2 = tid>>3, cb = (tid&7)*3;
#pragma unroll
    for (int e=0;e<3;++e){
        int col = c0 + cb + e;
        int n = col & (H-1);
        int o = b2*H + n;
        if (col < 512){
            if (t >= 0){
                float pre = s[e] + ldc(&xgo[o]);
                float ht = tanhf(pre);
                float z  = ldc(&zbuf[o]);
                float hp = ldc(&hbuf[o]);
                float hn = (1.f - z)*ht + z*hp;
                stc(&hbuf[o], hn);
                stc(&out[((size_t)b2*SEQ + t)*H + n], hn);
                if (t == SEQ-1)
                    stc(&out[(size_t)B*SEQ*H + b2*(2*H) + PASS*H + n], hn);
            }
        } else if (t+1 < SEQ){
            if (col < 1024) stc(&xgz[o], s[e] + bz[n]);
            else            stc(&xgr[o], s[e] + br[n]);
        }
    }
}

__global__ __launch_bounds__(NT) void gru_kernel(
    const float* x,
    const float* Wz0, const float* bz0, const float* Wr0, const float* br0,
    const float* Wo0, const float* bo0,
    const float* Wz1, const float* bz1, const float* Wr1, const float* br1,
    const float* Wo1, const float* bo1,
    float* zbuf, float* rhbuf, float* xgz, float* xgr, float* xgo,
    float* hbuf0, float* hbuf1, unsigned* flags, float* out)
{
    __shared__ float xh0[CHUNK][B+1];
    __shared__ float xh1[CHUNK][B+1];
    __shared__ float red[B][8][25];
    unsigned gen = 0;

    // ---- pass 0 (layer 0, input x) ----
    phase2<0>(-1, x, Wz0, Wr0, Wo0, bz0, br0,
              zbuf, rhbuf, xgz, xgr, xgo, hbuf0, out, xh0, xh1, red);
    grid_sync(flags, ++gen);
    for (int t = 0; t < SEQ; ++t){
        phase1(t, x, Wz0, Wr0, Wo0, bo0,
               zbuf, rhbuf, xgz, xgr, xgo, hbuf0, xh0, xh1, red);
        grid_sync(flags, ++gen);
        phase2<0>(t, x, Wz0, Wr0, Wo0, bz0, br0,
                  zbuf, rhbuf, xgz, xgr, xgo, hbuf0, out, xh0, xh1, red);
        grid_sync(flags, ++gen);
    }
    // ---- pass 1 (layer 1, input y0 = out) ----
    phase2<1>(-1, out, Wz1, Wr1, Wo1, bz1, br1,
              zbuf, rhbuf, xgz, xgr, xgo, hbuf1, out, xh0, xh1, red);
    grid_sync(flags, ++gen);
    for (int t = 0; t < SEQ; ++t){
        phase1(t, out, Wz1, Wr1, Wo1, bo1,
               zbuf, rhbuf, xgz, xgr, xgo, hbuf1, xh0, xh1, red);
        grid_sync(flags, ++gen);
        phase2<1>(t, out, Wz1, Wr1, Wo1, bz1, br1,
                  zbuf, rhbuf, xgz, xgr, xgo, hbuf1, out, xh0, xh1, red);
        grid_sync(flags, ++gen);
    }
}

__global__ void init_kernel(const float* h0, float* hbuf0, float* hbuf1,
                            unsigned* flags){
    int idx = blockIdx.x * blockDim.x + threadIdx.x;
    int nthr = gridDim.x * blockDim.x;
    for (int i = idx; i < B*H; i += nthr){
        int b = i >> 9, n = i & 511;
        hbuf0[i] = h0[b*1024 + n];          // h0[b][0][n]
        hbuf1[i] = h0[b*1024 + 512 + n];    // h0[b][1][n]
    }
    for (int i = idx; i < (NWG+1)*FLAG_STRIDE; i += nthr) flags[i] = 0;
}

extern "C" void kernel_launch(void* const* d_in, const int* in_sizes, int n_in,
                              void* d_out, int out_size, void* d_ws, size_t ws_size,
                              hipStream_t stream) {
    const float* x   = (const float*)d_in[0];
    const float* h0  = (const float*)d_in[1];
    const float* Wz0 = (const float*)d_in[2];
    const float* bz0 = (const float*)d_in[3];
    const float* Wr0 = (const float*)d_in[4];
    const float* br0 = (const float*)d_in[5];
    const float* Wo0 = (const float*)d_in[6];
    const float* bo0 = (const float*)d_in[7];
    const float* Wz1 = (const float*)d_in[8];
    const float* bz1 = (const float*)d_in[9];
    const float* Wr1 = (const float*)d_in[10];
    const float* br1 = (const float*)d_in[11];
    const float* Wo1 = (const float*)d_in[12];
    const float* bo1 = (const float*)d_in[13];
    float* out = (float*)d_out;

    char* ws = (char*)d_ws;
    float* zbuf     = (float*)(ws);             // 64KB [32][512]
    float* rhbuf    = (float*)(ws + 0x10000);   // 64KB
    float* xgz      = (float*)(ws + 0x20000);   // 64KB
    float* xgr      = (float*)(ws + 0x30000);   // 64KB
    float* xgo      = (float*)(ws + 0x40000);   // 64KB
    float* hbuf0    = (float*)(ws + 0x50000);   // 64KB
    float* hbuf1    = (float*)(ws + 0x60000);   // 64KB
    unsigned* flags = (unsigned*)(ws + 0x70000);// (64+1)*64B

    init_kernel<<<dim3(32), dim3(256), 0, stream>>>(h0, hbuf0, hbuf1, flags);
    gru_kernel<<<dim3(NWG), dim3(NT), 0, stream>>>(
        x, Wz0, bz0, Wr0, br0, Wo0, bo0,
        Wz1, bz1, Wr1, br1, Wo1, bo1,
        zbuf, rhbuf, xgz, xgr, xgo, hbuf0, hbuf1, flags, out);
}

// Round 7
// 50652.185 us; speedup vs baseline: 6.5230x; 6.5230x over previous
//
#include <hip/hip_runtime.h>
#include <math.h>

#define B 32
#define SEQ 1024
#define H 512
#define NWG 96
#define NT 256
#define COLS 32             // cols per WG: 96*32 = 3072 = 6 units x 512
#define PAD 516             // xh row stride in words; 516%32=4 -> conflict-free b128 reads

typedef float f4 __attribute__((ext_vector_type(4)));

__device__ __forceinline__ float sigf(float v){ return 1.0f/(1.0f+expf(-v)); }

// ---- coherent (LLC, cache-bypass) accessors: volatile -> sc0 sc1, no cache maintenance
__device__ __forceinline__ f4 ldc4(const float* p){ return *(const volatile f4*)p; }
__device__ __forceinline__ void stc4(float* p, f4 v){ *(volatile f4*)p = v; }
__device__ __forceinline__ unsigned ldcu(const unsigned* p){
    return __hip_atomic_load(p, __ATOMIC_RELAXED, __HIP_MEMORY_SCOPE_AGENT);
}
__device__ __forceinline__ void stcu(unsigned* p, unsigned v){
    __hip_atomic_store(p, v, __ATOMIC_RELAXED, __HIP_MEMORY_SCOPE_AGENT);
}

// ---- low-traffic barrier: 1 atomicAdd arrival/WG + 1-lane poll of ONE epoch line.
__device__ __forceinline__ void grid_sync(unsigned* cnt, unsigned* epoch, unsigned gen){
    asm volatile("s_waitcnt vmcnt(0)" ::: "memory");   // drain this wave's data stores
    __syncthreads();                                   // all waves of WG drained
    if (threadIdx.x == 0){
        unsigned old = __hip_atomic_fetch_add(cnt, 1u, __ATOMIC_RELAXED,
                                              __HIP_MEMORY_SCOPE_AGENT);
        if (old == gen * NWG + (NWG - 1))
            stcu(epoch, gen + 1);                      // last arriver opens the gate
        while (ldcu(epoch) < gen + 1)
            __builtin_amdgcn_s_sleep(2);               // ~128 cyc backoff
    }
    __syncthreads();
}

// ---- stage A[32][512] (row stride rs) into LDS xh[b][k]; 8 loads in flight
template<bool COH>
__device__ __forceinline__ void stage(float (*xh)[PAD], const float* src, size_t rs){
    const int tid = threadIdx.x;
    const int b = tid >> 3;          // 0..31
    const int j = tid & 7;           // 0..7
    const float* rp = src + (size_t)b * rs;
    f4 v[8];
#pragma unroll
    for (int half = 0; half < 2; ++half){
#pragma unroll
        for (int i = 0; i < 8; ++i){
            int q = j + 8*(half*8 + i);          // float4 index in row, 0..127
            v[i] = COH ? ldc4(rp + 4*q) : *(const f4*)(rp + 4*q);
        }
#pragma unroll
        for (int i = 0; i < 8; ++i){
            int q = j + 8*(half*8 + i);
            *(f4*)&xh[b][4*q] = v[i];
        }
    }
}

// ---- per-thread 4-column GEMM: thread (b=tid>>3, cg=tid&7) -> cols n0+cg*4..+3
__device__ __forceinline__ f4 matcol(const float* W /* +n0 folded */, const float (*xh)[PAD]){
    const int tid = threadIdx.x;
    const int b = tid >> 3, cg = tid & 7;
    const float* wp = W + cg*4;
    const float* xr = xh[b];
    f4 acc = {0.f,0.f,0.f,0.f};
#pragma unroll 8
    for (int k = 0; k < H; k += 4){
        f4 xv = *(const f4*)(xr + k);            // ds_read_b128, conflict-free
        f4 w0 = *(const f4*)(wp + (size_t)k*H);
        f4 w1 = *(const f4*)(wp + (size_t)(k+1)*H);
        f4 w2 = *(const f4*)(wp + (size_t)(k+2)*H);
        f4 w3 = *(const f4*)(wp + (size_t)(k+3)*H);
        acc += xv.x*w0; acc += xv.y*w1; acc += xv.z*w2; acc += xv.w*w3;
    }
    return acc;
}

struct Bufs {
    const float* x; float* out;
    const float* Wz[2]; const float* Wr[2]; const float* Wo[2];
    const float* bz[2]; const float* br[2]; const float* bo[2];
    float* zb[2]; float* rhb[2]; float* xgz[2]; float* xgr[2]; float* xgo[2]; float* hb[2];
};

// ---- P1(u): per layer {z_h, r_h, xgo(t)};  units: 0..2 = layer0, 3..5 = layer1
__device__ void phase1(int u, const Bufs& bf, float (*xh)[PAD]){
    const int wg = blockIdx.x;
    const int unit = wg >> 4, n0 = (wg & 15) * COLS;
    const int l = unit >= 3 ? 1 : 0;
    const int role = unit - 3*l;                 // 0:z_h 1:r_h 2:xgo
    const int t = l ? (u - 2) : u;
    if (t < 0 || t >= SEQ) return;

    if (role == 2){
        const float* A = (l ? bf.out : bf.x) + (size_t)t * H;
        if (l) stage<true >(xh, A, (size_t)SEQ*H);
        else   stage<false>(xh, A, (size_t)SEQ*H);
    } else {
        stage<true>(xh, bf.hb[l], H);
    }
    __syncthreads();

    const float* W = (role == 0) ? bf.Wz[l] + (size_t)H*H
                   : (role == 1) ? bf.Wr[l] + (size_t)H*H
                   :               bf.Wo[l];
    f4 s = matcol(W + n0, xh);

    const int tid = threadIdx.x;
    const int b = tid >> 3, cg = tid & 7;
    const int n = n0 + cg*4, o = b*H + n;
    if (role == 0){
        f4 g = ldc4(&bf.xgz[l][o]);
        f4 z; z.x=sigf(s.x+g.x); z.y=sigf(s.y+g.y); z.z=sigf(s.z+g.z); z.w=sigf(s.w+g.w);
        stc4(&bf.zb[l][o], z);
    } else if (role == 1){
        f4 g = ldc4(&bf.xgr[l][o]);
        f4 h = ldc4(&bf.hb[l][o]);
        f4 r; r.x=sigf(s.x+g.x)*h.x; r.y=sigf(s.y+g.y)*h.y;
              r.z=sigf(s.z+g.z)*h.z; r.w=sigf(s.w+g.w)*h.w;
        stc4(&bf.rhb[l][o], r);
    } else {
        f4 bv = *(const f4*)&bf.bo[l][n];
        stc4(&bf.xgo[l][o], s + bv);
    }
}

// ---- P2(u): per layer {o_h + h-update + y write, xgz(t+1), xgr(t+1)}
__device__ void phase2(int u, const Bufs& bf, float (*xh)[PAD]){
    const int wg = blockIdx.x;
    const int unit = wg >> 4, n0 = (wg & 15) * COLS;
    const int l = unit >= 3 ? 1 : 0;
    const int role = unit - 3*l;                 // 0:o_h 1:xgz 2:xgr
    const int t = l ? (u - 2) : u;

    const int tid = threadIdx.x;
    const int b = tid >> 3, cg = tid & 7;
    const int n = n0 + cg*4, o = b*H + n;

    if (role == 0){
        if (t < 0 || t >= SEQ) return;
        stage<true>(xh, bf.rhb[l], H);
        __syncthreads();
        f4 s = matcol(bf.Wo[l] + (size_t)H*H + n0, xh);
        f4 go = ldc4(&bf.xgo[l][o]);
        f4 z  = ldc4(&bf.zb[l][o]);
        f4 hp = ldc4(&bf.hb[l][o]);
        f4 hn;
        hn.x = (1.f-z.x)*tanhf(s.x+go.x) + z.x*hp.x;
        hn.y = (1.f-z.y)*tanhf(s.y+go.y) + z.y*hp.y;
        hn.z = (1.f-z.z)*tanhf(s.z+go.z) + z.z*hp.z;
        hn.w = (1.f-z.w)*tanhf(s.w+go.w) + z.w*hp.w;
        stc4(&bf.hb[l][o], hn);
        stc4(&bf.out[((size_t)b*SEQ + t)*H + n], hn);   // y_l[t] (y1 overwrites y0 slice)
        if (t == SEQ-1)
            stc4(&bf.out[(size_t)B*SEQ*H + b*(2*H) + l*H + n], hn);
    } else {
        const int tn = t + 1;
        if (tn < 0 || tn >= SEQ) return;
        const float* A = (l ? bf.out : bf.x) + (size_t)tn * H;
        if (l) stage<true >(xh, A, (size_t)SEQ*H);
        else   stage<false>(xh, A, (size_t)SEQ*H);
        __syncthreads();
        const float* W = (role == 1) ? bf.Wz[l] : bf.Wr[l];   // x-rows
        f4 s = matcol(W + n0, xh);
        const float* bb = (role == 1) ? bf.bz[l] : bf.br[l];
        f4 bv = *(const f4*)&bb[n];
        if (role == 1) stc4(&bf.xgz[l][o], s + bv);
        else           stc4(&bf.xgr[l][o], s + bv);
    }
}

__global__ __launch_bounds__(NT) void gru_kernel(
    const float* x,
    const float* Wz0, const float* bz0, const float* Wr0, const float* br0,
    const float* Wo0, const float* bo0,
    const float* Wz1, const float* bz1, const float* Wr1, const float* br1,
    const float* Wo1, const float* bo1,
    float* wsf, unsigned* cnt, unsigned* epoch, float* out)
{
    __shared__ float xh[B][PAD];
    Bufs bf;
    bf.x = x; bf.out = out;
    bf.Wz[0]=Wz0; bf.Wz[1]=Wz1; bf.Wr[0]=Wr0; bf.Wr[1]=Wr1; bf.Wo[0]=Wo0; bf.Wo[1]=Wo1;
    bf.bz[0]=bz0; bf.bz[1]=bz1; bf.br[0]=br0; bf.br[1]=br1; bf.bo[0]=bo0; bf.bo[1]=bo1;
    const int SL = B*H;   // 16384 floats per buffer
    bf.zb[0]=wsf;        bf.zb[1]=wsf+SL;   bf.rhb[0]=wsf+2*SL; bf.rhb[1]=wsf+3*SL;
    bf.xgz[0]=wsf+4*SL;  bf.xgz[1]=wsf+5*SL; bf.xgr[0]=wsf+6*SL; bf.xgr[1]=wsf+7*SL;
    bf.xgo[0]=wsf+8*SL;  bf.xgo[1]=wsf+9*SL; bf.hb[0]=wsf+10*SL; bf.hb[1]=wsf+11*SL;

    unsigned gen = 0;
    phase2(-1, bf, xh);                 // prologue: xgz0/xgr0 for t=0
    grid_sync(cnt, epoch, gen); ++gen;
    for (int u = 0; u <= SEQ+1; ++u){
        phase1(u, bf, xh);
        grid_sync(cnt, epoch, gen); ++gen;
        phase2(u, bf, xh);
        grid_sync(cnt, epoch, gen); ++gen;
    }
}

__global__ void init_kernel(const float* h0, float* wsf, unsigned* cnt, unsigned* epoch){
    int idx = blockIdx.x * blockDim.x + threadIdx.x;
    int nthr = gridDim.x * blockDim.x;
    const int SL = B*H;
    float* hb0 = wsf + 10*SL;
    float* hb1 = wsf + 11*SL;
    for (int i = idx; i < B*H; i += nthr){
        int b = i >> 9, n = i & 511;
        hb0[i] = h0[b*1024 + n];          // h0[b][0][n]
        hb1[i] = h0[b*1024 + 512 + n];    // h0[b][1][n]
    }
    if (idx == 0){ *cnt = 0u; *epoch = 0u; }
}

extern "C" void kernel_launch(void* const* d_in, const int* in_sizes, int n_in,
                              void* d_out, int out_size, void* d_ws, size_t ws_size,
                              hipStream_t stream) {
    const float* x   = (const float*)d_in[0];
    const float* h0  = (const float*)d_in[1];
    const float* Wz0 = (const float*)d_in[2];
    const float* bz0 = (const float*)d_in[3];
    const float* Wr0 = (const float*)d_in[4];
    const float* br0 = (const float*)d_in[5];
    const float* Wo0 = (const float*)d_in[6];
    const float* bo0 = (const float*)d_in[7];
    const float* Wz1 = (const float*)d_in[8];
    const float* bz1 = (const float*)d_in[9];
    const float* Wr1 = (const float*)d_in[10];
    const float* br1 = (const float*)d_in[11];
    const float* Wo1 = (const float*)d_in[12];
    const float* bo1 = (const float*)d_in[13];
    float* out = (float*)d_out;

    char* ws = (char*)d_ws;
    float* wsf = (float*)ws;                          // 12 x 64KB buffers
    unsigned* cnt   = (unsigned*)(ws + 12*B*H*4);     // arrival counter (own line)
    unsigned* epoch = (unsigned*)(ws + 12*B*H*4 + 256); // gate (own line)

    init_kernel<<<dim3(32), dim3(256), 0, stream>>>(h0, wsf, cnt, epoch);
    gru_kernel<<<dim3(NWG), dim3(NT), 0, stream>>>(
        x, Wz0, bz0, Wr0, br0, Wo0, bo0,
        Wz1, bz1, Wr1, br1, Wo1, bo1,
        wsf, cnt, epoch, out);
}